// Round 10
// baseline (96.739 us; speedup 1.0000x reference)
//
#include <hip/hip_runtime.h>
#include <hip/hip_fp16.h>

#define BB 16
#define NN 4096
#define CC 6
#define NSEG (BB * NN)          // 65536 points per direction-role
#define NTILE 128               // 4096 cols / 32
#define NBLK 1024               // min-kernel blocks

using half8  = __attribute__((ext_vector_type(8))) _Float16;
using f32x16 = __attribute__((ext_vector_type(16))) float;

// Single MFMA in asm: D forced to arch VGPRs ("=&v" early-clobber so D never
// aliases A/B/C), C (zeros) is a read-only input and stays pristine across all
// 128 calls. s_nop 1 up front covers VALU-write->MFMA-read on B (prefetch mov);
// 3x s_nop 7 (24 cyc) covers MFMA-write->VALU-read (16-pass needs ~18).
#define MFMA1(d, a, b, c)                                              \
    asm("s_nop 1\n\t"                                                  \
        "v_mfma_f32_32x32x16_f16 %0, %1, %2, %3\n\t"                   \
        "s_nop 7\n\t"                                                  \
        "s_nop 7\n\t"                                                  \
        "s_nop 7"                                                      \
        : "=&v"(d) : "v"(a), "v"(b), "v"(c))

// ws layout:
//   half8 Af[2][BB][NN] @ 0     (2 MB) A entry per ROW point: (-2h0,-2h1,-2h2,1,1,0,0,0)
//   half8 Bf[2][BB][NN] @ 2 MB  (2 MB) B entry per COL point: ( h0, h1, h2,hi,lo,0,0,0)
//   float rx[2][BB][NN] @ 4 MB  (512 KB) row-point |h|^2 fp32 (absorbs tail over-read)
//   float bpart[NBLK]   @ 4.5MB (4 KB) per-block partials

__global__ __launch_bounds__(256) void chamfer_prep_kernel(
    const float* __restrict__ xg, const float* __restrict__ yg,
    half8* __restrict__ Af, half8* __restrict__ Bf, float* __restrict__ rx)
{
    const int p   = blockIdx.x * 256 + threadIdx.x;   // 0..131071
    const int dir = p >> 16;
    const int rem = p & (NSEG - 1);
    const float* __restrict__ R  = dir ? yg : xg;   // row cloud (min FOR its points)
    const float* __restrict__ Cl = dir ? xg : yg;   // col cloud (min OVER its points)

    {   // row side
        const float c0 = R[(size_t)rem * CC + 0];
        const float c1 = R[(size_t)rem * CC + 1];
        const float c2 = R[(size_t)rem * CC + 2];
        const _Float16 h0 = (_Float16)c0, h1 = (_Float16)c1, h2 = (_Float16)c2;
        const float f0 = (float)h0, f1 = (float)h1, f2 = (float)h2;
        rx[p] = fmaf(f0, f0, fmaf(f1, f1, f2 * f2));
        half8 a = { (_Float16)(-2.0f) * h0, (_Float16)(-2.0f) * h1,
                    (_Float16)(-2.0f) * h2, (_Float16)1.0f, (_Float16)1.0f,
                    (_Float16)0.0f, (_Float16)0.0f, (_Float16)0.0f };
        Af[p] = a;
    }
    {   // col side: ry as hi/lo fp16 pair in K-slots 3,4
        const float c0 = Cl[(size_t)rem * CC + 0];
        const float c1 = Cl[(size_t)rem * CC + 1];
        const float c2 = Cl[(size_t)rem * CC + 2];
        const _Float16 h0 = (_Float16)c0, h1 = (_Float16)c1, h2 = (_Float16)c2;
        const float f0 = (float)h0, f1 = (float)h1, f2 = (float)h2;
        const float r  = fmaf(f0, f0, fmaf(f1, f1, f2 * f2));
        const _Float16 hi = (_Float16)r;
        const _Float16 lo = (_Float16)(r - (float)hi);
        half8 bfr = { h0, h1, h2, hi, lo,
                      (_Float16)0.0f, (_Float16)0.0f, (_Float16)0.0f };
        Bf[p] = bfr;
    }
}

// grid = 1024 blocks x 256 thr (4 waves). wave -> (dir, b, rowgroup of 32); full j-range.
__global__ __launch_bounds__(256, 4) void chamfer_min_kernel(
    const half8* __restrict__ Af, const half8* __restrict__ Bf,
    const float* __restrict__ rx, float* __restrict__ bpart)
{
    const int bid  = blockIdx.x;
    const int dir  = bid & 1;
    const int b    = (bid >> 1) & 15;
    const int gq   = bid >> 5;                 // 0..31
    const int tid  = threadIdx.x;
    const int w    = tid >> 6;
    const int lane = tid & 63;
    const int l31  = lane & 31;
    const int hf   = lane >> 5;                // K-half select for A (upper = zeros)
    const int g    = gq * 4 + w;               // rowgroup 0..127

    const size_t base = ((size_t)dir << 16) + ((size_t)b << 12);

    half8 a = {};
    if (hf == 0) a = Af[base + (size_t)g * 32 + l31];   // one-time guarded load

    // B loads unguarded: lanes 32..63 feed k=8..15, which A zeroes out.
    const half8* __restrict__ pb = Bf + base + l31;

    const f32x16 zc = {};                      // read-only zero C, pinned in VGPRs
    float mn[16];
    #pragma unroll
    for (int s = 0; s < 16; ++s) mn[s] = 3.4e38f;

    half8 b0 = pb[0];
    half8 b1 = pb[32];
    half8 b2 = pb[64];
    half8 b3 = pb[96];
    const half8* pf = pb + 128;

    for (int jt = 0; jt < NTILE; jt += 4) {
        f32x16 d0, d1;
        MFMA1(d0, a, b0, zc);
        MFMA1(d1, a, b1, zc);
        const half8 n0 = pf[0];                 // prefetch tiles jt+4, jt+5
        const half8 n1 = pf[32];
        #pragma unroll
        for (int s = 0; s < 16; ++s)
            mn[s] = fminf(mn[s], fminf(d0[s], d1[s]));   // -> v_min3_f32 on VGPRs

        f32x16 e0, e1;
        MFMA1(e0, a, b2, zc);
        MFMA1(e1, a, b3, zc);
        const half8 n2 = pf[64];                // prefetch tiles jt+6, jt+7
        const half8 n3 = pf[96];
        #pragma unroll
        for (int s = 0; s < 16; ++s)
            mn[s] = fminf(mn[s], fminf(e0[s], e1[s]));

        b0 = n0; b1 = n1; b2 = n2; b3 = n3;
        pf += 128;
        // final-iter prefetch over-reads <=2KB past Bf into rx region: valid ws
    }

    // cross-lane min over the 32 cols within each half (halves hold different rows)
    #pragma unroll
    for (int s = 0; s < 16; ++s) {
        float v = mn[s];
        v = fminf(v, __shfl_xor(v, 1,  64));
        v = fminf(v, __shfl_xor(v, 2,  64));
        v = fminf(v, __shfl_xor(v, 4,  64));
        v = fminf(v, __shfl_xor(v, 8,  64));
        v = fminf(v, __shfl_xor(v, 16, 64));
        mn[s] = v;
    }

    // add rx per row, sum this half's 16 rows
    const float* __restrict__ rxb = rx + base + (size_t)g * 32;
    float s16 = 0.0f;
    #pragma unroll
    for (int s = 0; s < 16; ++s) {
        const int row = (s & 3) + 8 * (s >> 2) + 4 * hf;  // C/D row map (m101)
        s16 += fmaxf(mn[s] + rxb[row], 0.0f);             // clamp fp noise at 0
    }

    __shared__ float hsum[8];
    if (l31 == 0) hsum[w * 2 + hf] = s16;
    __syncthreads();
    if (tid == 0) {
        float t = 0.0f;
        #pragma unroll
        for (int k = 0; k < 8; ++k) t += hsum[k];
        bpart[bid] = t;            // plain store — no atomics anywhere
    }
}

__global__ __launch_bounds__(256) void chamfer_final_kernel(
    const float* __restrict__ bpart, float* __restrict__ out)
{
    const int tid = threadIdx.x;
    float s = bpart[tid] + bpart[tid + 256] + bpart[tid + 512] + bpart[tid + 768];
    for (int off = 32; off > 0; off >>= 1)
        s += __shfl_down(s, off, 64);
    __shared__ float wsum[4];
    if ((tid & 63) == 0) wsum[tid >> 6] = s;
    __syncthreads();
    if (tid == 0)
        out[0] = (wsum[0] + wsum[1] + wsum[2] + wsum[3]) * (1.0f / NSEG);
}

extern "C" void kernel_launch(void* const* d_in, const int* in_sizes, int n_in,
                              void* d_out, int out_size, void* d_ws, size_t ws_size,
                              hipStream_t stream) {
    const float* x = (const float*)d_in[0];
    const float* y = (const float*)d_in[1];
    float* out = (float*)d_out;

    half8* Af = (half8*)d_ws;
    half8* Bf = (half8*)((char*)d_ws + (size_t)2 * NSEG * sizeof(half8));
    float* rx = (float*)((char*)d_ws + (size_t)4 * NSEG * sizeof(half8));
    float* bpart = (float*)((char*)rx + (size_t)2 * NSEG * sizeof(float));

    chamfer_prep_kernel<<<2 * NSEG / 256, 256, 0, stream>>>(x, y, Af, Bf, rx);
    chamfer_min_kernel<<<NBLK, 256, 0, stream>>>(Af, Bf, rx, bpart);
    chamfer_final_kernel<<<1, 256, 0, stream>>>(bpart, out);
}

// Round 11
// 96.367 us; speedup vs baseline: 1.0039x; 1.0039x over previous
//
#include <hip/hip_runtime.h>
#include <hip/hip_fp16.h>

#define BB 16
#define NN 4096
#define CC 6
#define NSEG (BB * NN)          // 65536 points per direction-role
#define NTILE 128               // 4096 cols / 32
#define NBLK 1024               // min-kernel blocks

using half8  = __attribute__((ext_vector_type(8))) _Float16;
using f32x16 = __attribute__((ext_vector_type(16))) float;

// Two MFMAs in one asm block. BOTH outputs early-clobbered ("=&v") so neither
// can alias any input (R8's bug). Hazard padding: second MFMA needs ~18 cyc
// before a VALU read of its D; 2x s_nop 7 + s_nop 6 = 23 cyc covers both.
// s_nop 1 up front covers any VALU write -> MFMA src read.
#define MFMA2(d0, d1, a, b0, b1, c)                                    \
    asm("s_nop 1\n\t"                                                  \
        "v_mfma_f32_32x32x16_f16 %0, %2, %3, %5\n\t"                   \
        "v_mfma_f32_32x32x16_f16 %1, %2, %4, %5\n\t"                   \
        "s_nop 7\n\t"                                                  \
        "s_nop 7\n\t"                                                  \
        "s_nop 6"                                                      \
        : "=&v"(d0), "=&v"(d1)                                         \
        : "v"(a), "v"(b0), "v"(b1), "v"(c))

// ws layout:
//   half8 Af[2][BB][NN] @ 0     (2 MB) A entry per ROW point: (-2h0,-2h1,-2h2,1,1,0,0,0)
//   half8 Bf[2][BB][NN] @ 2 MB  (2 MB) B entry per COL point: ( h0, h1, h2,hi,lo,0,0,0)
//   float rx[2][BB][NN] @ 4 MB  (512 KB) row-point |h|^2 fp32 (absorbs tail over-read)
//   float bpart[NBLK]   @ 4.5MB (4 KB) per-block partials

__global__ __launch_bounds__(256) void chamfer_prep_kernel(
    const float* __restrict__ xg, const float* __restrict__ yg,
    half8* __restrict__ Af, half8* __restrict__ Bf, float* __restrict__ rx)
{
    const int p   = blockIdx.x * 256 + threadIdx.x;   // 0..131071
    const int dir = p >> 16;
    const int rem = p & (NSEG - 1);
    const float* __restrict__ R  = dir ? yg : xg;   // row cloud (min FOR its points)
    const float* __restrict__ Cl = dir ? xg : yg;   // col cloud (min OVER its points)

    {   // row side
        const float c0 = R[(size_t)rem * CC + 0];
        const float c1 = R[(size_t)rem * CC + 1];
        const float c2 = R[(size_t)rem * CC + 2];
        const _Float16 h0 = (_Float16)c0, h1 = (_Float16)c1, h2 = (_Float16)c2;
        const float f0 = (float)h0, f1 = (float)h1, f2 = (float)h2;
        rx[p] = fmaf(f0, f0, fmaf(f1, f1, f2 * f2));
        half8 a = { (_Float16)(-2.0f) * h0, (_Float16)(-2.0f) * h1,
                    (_Float16)(-2.0f) * h2, (_Float16)1.0f, (_Float16)1.0f,
                    (_Float16)0.0f, (_Float16)0.0f, (_Float16)0.0f };
        Af[p] = a;
    }
    {   // col side: ry as hi/lo fp16 pair in K-slots 3,4
        const float c0 = Cl[(size_t)rem * CC + 0];
        const float c1 = Cl[(size_t)rem * CC + 1];
        const float c2 = Cl[(size_t)rem * CC + 2];
        const _Float16 h0 = (_Float16)c0, h1 = (_Float16)c1, h2 = (_Float16)c2;
        const float f0 = (float)h0, f1 = (float)h1, f2 = (float)h2;
        const float r  = fmaf(f0, f0, fmaf(f1, f1, f2 * f2));
        const _Float16 hi = (_Float16)r;
        const _Float16 lo = (_Float16)(r - (float)hi);
        half8 bfr = { h0, h1, h2, hi, lo,
                      (_Float16)0.0f, (_Float16)0.0f, (_Float16)0.0f };
        Bf[p] = bfr;
    }
}

// grid = 1024 blocks x 256 thr (4 waves). wave -> (dir, b, rowgroup of 32); full j-range.
__global__ __launch_bounds__(256, 4) void chamfer_min_kernel(
    const half8* __restrict__ Af, const half8* __restrict__ Bf,
    const float* __restrict__ rx, float* __restrict__ bpart)
{
    const int bid  = blockIdx.x;
    const int dir  = bid & 1;
    const int b    = (bid >> 1) & 15;
    const int gq   = bid >> 5;                 // 0..31
    const int tid  = threadIdx.x;
    const int w    = tid >> 6;
    const int lane = tid & 63;
    const int l31  = lane & 31;
    const int hf   = lane >> 5;                // K-half select for A (upper = zeros)
    const int g    = gq * 4 + w;               // rowgroup 0..127

    const size_t base = ((size_t)dir << 16) + ((size_t)b << 12);

    half8 a = {};
    if (hf == 0) a = Af[base + (size_t)g * 32 + l31];   // one-time guarded load

    // B loads unguarded: lanes 32..63 feed k=8..15, which A zeroes out.
    const half8* __restrict__ pb = Bf + base + l31;

    f32x16 zc = {};
    asm volatile("" : "+v"(zc));               // pin: asm-defined, cannot rematerialize

    float mn[16];
    #pragma unroll
    for (int s = 0; s < 16; ++s) mn[s] = 3.4e38f;

    half8 b0 = pb[0];
    half8 b1 = pb[32];
    half8 b2 = pb[64];
    half8 b3 = pb[96];
    const half8* pf = pb + 128;

    for (int jt = 0; jt < NTILE; jt += 4) {
        f32x16 d0, d1;
        MFMA2(d0, d1, a, b0, b1, zc);
        b0 = pf[0];                             // prefetch tiles jt+4, jt+5
        b1 = pf[32];                            // (VMEM writeback >> MFMA read window)
        #pragma unroll
        for (int s = 0; s < 16; ++s)
            mn[s] = fminf(mn[s], fminf(d0[s], d1[s]));   // -> v_min3_f32 on VGPRs

        MFMA2(d0, d1, a, b2, b3, zc);
        b2 = pf[64];                            // prefetch tiles jt+6, jt+7
        b3 = pf[96];
        #pragma unroll
        for (int s = 0; s < 16; ++s)
            mn[s] = fminf(mn[s], fminf(d0[s], d1[s]));

        pf += 128;
        // final-iter prefetch over-reads <=2KB past Bf into rx region: valid ws
    }

    // cross-lane min over the 32 cols within each half (halves hold different rows)
    #pragma unroll
    for (int s = 0; s < 16; ++s) {
        float v = mn[s];
        v = fminf(v, __shfl_xor(v, 1,  64));
        v = fminf(v, __shfl_xor(v, 2,  64));
        v = fminf(v, __shfl_xor(v, 4,  64));
        v = fminf(v, __shfl_xor(v, 8,  64));
        v = fminf(v, __shfl_xor(v, 16, 64));
        mn[s] = v;
    }

    // add rx per row, sum this half's 16 rows
    const float* __restrict__ rxb = rx + base + (size_t)g * 32;
    float s16 = 0.0f;
    #pragma unroll
    for (int s = 0; s < 16; ++s) {
        const int row = (s & 3) + 8 * (s >> 2) + 4 * hf;  // C/D row map (m101)
        s16 += fmaxf(mn[s] + rxb[row], 0.0f);             // clamp fp noise at 0
    }

    __shared__ float hsum[8];
    if (l31 == 0) hsum[w * 2 + hf] = s16;
    __syncthreads();
    if (tid == 0) {
        float t = 0.0f;
        #pragma unroll
        for (int k = 0; k < 8; ++k) t += hsum[k];
        bpart[bid] = t;            // plain store — no atomics anywhere
    }
}

__global__ __launch_bounds__(256) void chamfer_final_kernel(
    const float* __restrict__ bpart, float* __restrict__ out)
{
    const int tid = threadIdx.x;
    float s = bpart[tid] + bpart[tid + 256] + bpart[tid + 512] + bpart[tid + 768];
    for (int off = 32; off > 0; off >>= 1)
        s += __shfl_down(s, off, 64);
    __shared__ float wsum[4];
    if ((tid & 63) == 0) wsum[tid >> 6] = s;
    __syncthreads();
    if (tid == 0)
        out[0] = (wsum[0] + wsum[1] + wsum[2] + wsum[3]) * (1.0f / NSEG);
}

extern "C" void kernel_launch(void* const* d_in, const int* in_sizes, int n_in,
                              void* d_out, int out_size, void* d_ws, size_t ws_size,
                              hipStream_t stream) {
    const float* x = (const float*)d_in[0];
    const float* y = (const float*)d_in[1];
    float* out = (float*)d_out;

    half8* Af = (half8*)d_ws;
    half8* Bf = (half8*)((char*)d_ws + (size_t)2 * NSEG * sizeof(half8));
    float* rx = (float*)((char*)d_ws + (size_t)4 * NSEG * sizeof(half8));
    float* bpart = (float*)((char*)rx + (size_t)2 * NSEG * sizeof(float));

    chamfer_prep_kernel<<<2 * NSEG / 256, 256, 0, stream>>>(x, y, Af, Bf, rx);
    chamfer_min_kernel<<<NBLK, 256, 0, stream>>>(Af, Bf, rx, bpart);
    chamfer_final_kernel<<<1, 256, 0, stream>>>(bpart, out);
}